// Round 11
// baseline (182.131 us; speedup 1.0000x reference)
//
#include <hip/hip_runtime.h>

#define B 2
#define S 2048
#define H 768
#define NH 12
#define HD 64
#define BS (B * S)
#define LOG2E 1.4426950408889634f

typedef unsigned short u16;
typedef unsigned int u32;
typedef short short8 __attribute__((ext_vector_type(8)));
typedef float f32x4 __attribute__((ext_vector_type(4)));
typedef float f32x16 __attribute__((ext_vector_type(16)));

// fp32 -> bf16 round-to-nearest-even
__device__ __forceinline__ u16 f2bf(float f) {
    union { float f; unsigned u; } c; c.f = f;
    unsigned u = c.u + 0x7FFFu + ((c.u >> 16) & 1u);
    return (u16)(u >> 16);
}
__device__ __forceinline__ float bf2f(u16 h) {
    union { unsigned u; float f; } c; c.u = ((unsigned)h) << 16;
    return c.f;
}
__device__ __forceinline__ f32x16 zero16() {
    f32x16 v;
    #pragma unroll
    for (int i = 0; i < 16; ++i) v[i] = 0.f;
    return v;
}
union pk4 { uint4 u; short8 s; };

// async global->LDS DMA, 16 B per lane; lds dest = wave-uniform base + lane*16
__device__ __forceinline__ void g2l16(const u16* g, u16* l) {
    __builtin_amdgcn_global_load_lds(
        (const __attribute__((address_space(1))) void*)g,
        (__attribute__((address_space(3))) void*)l, 16, 0, 0);
}

// ---------------------------------------------------------------------------
// Merged prep: blocks [0,576) transpose+convert weights (RoPE folded into
// Wq/Wk per the reference's head-indexed-table quirk; Q also folds
// 0.125*log2e); blocks [576,2112) convert hidden_states fp32->bf16.
// ---------------------------------------------------------------------------
__global__ __launch_bounds__(256) void prep_kernel(
    const float* __restrict__ hs,
    const float* __restrict__ Wq, const float* __restrict__ Wk,
    const float* __restrict__ Wv, const float* __restrict__ Wo,
    const float* __restrict__ bq, const float* __restrict__ bk,
    const float* __restrict__ cosp, const float* __restrict__ sinp,
    u16* __restrict__ hsb, u16* __restrict__ WTqkv, u16* __restrict__ WTo,
    float* __restrict__ bqk2)
{
    __shared__ float Lt[64 * 65];
    const int bid = blockIdx.x;
    const int t = threadIdx.x;

    if (bid >= 576) {                       // ---- hidden_states convert ----
        size_t i = ((size_t)(bid - 576) * 256 + t) * 8;
        float4 a = *(const float4*)(hs + i);
        float4 b = *(const float4*)(hs + i + 4);
        short8 p;
        p[0] = (short)f2bf(a.x); p[1] = (short)f2bf(a.y);
        p[2] = (short)f2bf(a.z); p[3] = (short)f2bf(a.w);
        p[4] = (short)f2bf(b.x); p[5] = (short)f2bf(b.y);
        p[6] = (short)f2bf(b.z); p[7] = (short)f2bf(b.w);
        *(short8*)(hsb + i) = p;
        return;
    }

    // ---- weight transpose (+RoPE fold for z<2) ----
    const int z   = bid / 144;
    const int rem = bid - z * 144;
    const int k0 = (rem / 12) * 64, n0 = (rem % 12) * 64;
    const float* W = (z == 0) ? Wq : (z == 1) ? Wk : (z == 2) ? Wv : Wo;
    u16* D = (z == 3) ? WTo : (WTqkv + (size_t)z * H * H);
    const int head = n0 >> 6;
    const float scl = (z == 0) ? (0.125f * LOG2E) : 1.0f;

    if (z < 2 && rem / 12 == 0 && t < 64) {   // rotated bias, once per col-tile
        const float* bs = (z == 0) ? bq : bk;
        int d = t;
        int pd = (d < 32) ? (2 * d + 1) : (2 * (d - 32));
        float sv = ((d < 32) ? -1.f : 1.f) * sinp[head * HD + d];
        float cv = cosp[head * HD + d];
        bqk2[z * H + n0 + d] = scl * (cv * bs[n0 + d] + sv * bs[n0 + pd]);
    }

    #pragma unroll
    for (int u = 0; u < 4; ++u) {
        int f = t + u * 256;
        int r = f >> 4, c4 = (f & 15) * 4;
        float4 w = *(const float4*)(W + (size_t)(k0 + r) * H + n0 + c4);
        Lt[r * 65 + c4 + 0] = w.x; Lt[r * 65 + c4 + 1] = w.y;
        Lt[r * 65 + c4 + 2] = w.z; Lt[r * 65 + c4 + 3] = w.w;
    }
    __syncthreads();
    #pragma unroll
    for (int u = 0; u < 4; ++u) {
        int f = t + u * 256;
        int n = f >> 4, k4 = (f & 15) * 4;
        ushort4 p;
        if (z < 2) {
            int pn = (n < 32) ? (2 * n + 1) : (2 * (n - 32));
            float cv = scl * cosp[head * HD + n];
            float sv = scl * ((n < 32) ? -1.f : 1.f) * sinp[head * HD + n];
            p.x = f2bf(cv * Lt[(k4 + 0) * 65 + n] + sv * Lt[(k4 + 0) * 65 + pn]);
            p.y = f2bf(cv * Lt[(k4 + 1) * 65 + n] + sv * Lt[(k4 + 1) * 65 + pn]);
            p.z = f2bf(cv * Lt[(k4 + 2) * 65 + n] + sv * Lt[(k4 + 2) * 65 + pn]);
            p.w = f2bf(cv * Lt[(k4 + 3) * 65 + n] + sv * Lt[(k4 + 3) * 65 + pn]);
        } else {
            p.x = f2bf(Lt[(k4 + 0) * 65 + n]);
            p.y = f2bf(Lt[(k4 + 1) * 65 + n]);
            p.z = f2bf(Lt[(k4 + 2) * 65 + n]);
            p.w = f2bf(Lt[(k4 + 3) * 65 + n]);
        }
        *(ushort4*)(D + (size_t)(n0 + n) * H + k0 + k4) = p;
    }
}

// ---------------------------------------------------------------------------
// Fused QKV GEMM, bf16 MFMA, DMA double-buffered (one barrier per K-slab),
// XOR-swizzled unpadded LDS. 1-D grid, m-block = bid % 32 (XCD-local A rows).
// Q stored TRANSPOSED ([b,h,d,s], like VT) — vector epilogue stores.
// ---------------------------------------------------------------------------
__global__ __launch_bounds__(256) void gemm_qkv_kernel(
    const u16* __restrict__ A, const u16* __restrict__ BT,
    const float* __restrict__ bqk2, const float* __restrict__ bv,
    u16* __restrict__ QTb, u16* __restrict__ Kb, u16* __restrict__ VT)
{
    __shared__ alignas(16) u16 Abuf[2][128 * 64];
    __shared__ alignas(16) u16 Bbuf[2][128 * 64];

    const int tid  = threadIdx.x;
    const int w    = tid >> 6;
    const int lane = tid & 63;
    const int quad = lane >> 4;
    const int l15  = lane & 15;
    const int wm = (w & 1) * 64, wn = (w >> 1) * 64;
    const int m0 = (blockIdx.x & 31) * 128;   // XCD-local m-slice
    const int n0 = (blockIdx.x >> 5) * 128;
    const int NK = H / 64;   // 12

    int srow[4], slc[4];
    #pragma unroll
    for (int u = 0; u < 4; ++u) {
        int s = u * 256 + tid;
        srow[u] = s >> 3;
        slc[u]  = (s & 7) ^ (srow[u] & 7);
    }

    #define QSTAGE(IT, NB)                                                    \
        _Pragma("unroll")                                                     \
        for (int u = 0; u < 4; ++u) {                                         \
            g2l16(A  + (size_t)(m0 + srow[u]) * H + (IT) * 64 + slc[u] * 8,   \
                  &Abuf[NB][(u * 256 + w * 64) * 8]);                         \
            g2l16(BT + (size_t)(n0 + srow[u]) * H + (IT) * 64 + slc[u] * 8,   \
                  &Bbuf[NB][(u * 256 + w * 64) * 8]);                         \
        }

    QSTAGE(0, 0)

    f32x4 acc[4][4];
    #pragma unroll
    for (int i = 0; i < 4; ++i)
        #pragma unroll
        for (int j = 0; j < 4; ++j) acc[i][j] = (f32x4){0.f, 0.f, 0.f, 0.f};

    for (int it = 0; it < NK; ++it) {
        const int cur = it & 1;
        __syncthreads();                       // drains DMA for buffer cur
        if (it + 1 < NK) { QSTAGE(it + 1, cur ^ 1) }

        const u16* Ac = Abuf[cur];
        const u16* Bc = Bbuf[cur];
        #pragma unroll
        for (int kc = 0; kc < 2; ++kc) {
            const int ch = kc * 4 + quad;
            short8 af[4], bf[4];
            #pragma unroll
            for (int mi = 0; mi < 4; ++mi) {
                int row = wm + mi * 16 + l15;
                af[mi] = *(const short8*)&Ac[row * 64 + (ch ^ (row & 7)) * 8];
            }
            #pragma unroll
            for (int ni = 0; ni < 4; ++ni) {
                int row = wn + ni * 16 + l15;
                bf[ni] = *(const short8*)&Bc[row * 64 + (ch ^ (row & 7)) * 8];
            }
            #pragma unroll
            for (int mi = 0; mi < 4; ++mi)
                #pragma unroll
                for (int ni = 0; ni < 4; ++ni)
                    acc[mi][ni] = __builtin_amdgcn_mfma_f32_16x16x32_bf16(
                        af[mi], bf[ni], acc[mi][ni], 0, 0, 0);
        }
    }
    #undef QSTAGE

    #pragma unroll
    for (int mi = 0; mi < 4; ++mi) {
        const int mbase = m0 + wm + mi * 16 + quad * 4;
        const int b_ = mbase >> 11, s = mbase & (S - 1);   // 4 rows same b
        #pragma unroll
        for (int ni = 0; ni < 4; ++ni) {
            const int col = n0 + wn + ni * 16 + l15;      // 0..2303
            const int which = col / H;
            const int c = col - which * H;
            const int h = c >> 6, d = c & 63;
            if (which != 1) {
                // Q (transposed) and V (transposed): vector store
                const float bias = (which == 2) ? bv[c] : bqk2[c];
                u16* dstT = (which == 2) ? VT : QTb;
                ushort4 pk;
                pk.x = f2bf(acc[mi][ni][0] + bias);
                pk.y = f2bf(acc[mi][ni][1] + bias);
                pk.z = f2bf(acc[mi][ni][2] + bias);
                pk.w = f2bf(acc[mi][ni][3] + bias);
                *(ushort4*)&dstT[(((size_t)b_ * NH + h) * HD + d) * S + s] = pk;
            } else {
                const float bias = bqk2[H + c];   // rotated (+scaled) K bias
                #pragma unroll
                for (int r = 0; r < 4; ++r) {
                    int m = mbase + r;
                    int bb = m >> 11, ss = m & (S - 1);
                    Kb[(((size_t)bb * NH + h) * S + ss) * HD + d] =
                        f2bf(acc[mi][ni][r] + bias);
                }
            }
        }
    }
}

// ---------------------------------------------------------------------------
// Output projection: out[4096,768] fp32 = ctxb @ WTo^T + bo. 128x64 tile,
// DMA double-buffered, XOR-swizzled LDS, m-block = bid % 32 (XCD-local).
// ---------------------------------------------------------------------------
__global__ __launch_bounds__(256) void gemm_out_kernel(
    const u16* __restrict__ A, const u16* __restrict__ BT,
    const float* __restrict__ bo, float* __restrict__ out)
{
    __shared__ alignas(16) u16 Abuf[2][128 * 64];
    __shared__ alignas(16) u16 Bbuf[2][64 * 64];

    const int tid  = threadIdx.x;
    const int w    = tid >> 6;
    const int lane = tid & 63;
    const int quad = lane >> 4;
    const int l15  = lane & 15;
    const int wm = (w & 1) * 64, wn = (w >> 1) * 32;
    const int m0 = (blockIdx.x & 31) * 128;   // XCD-local m-slice
    const int n0 = (blockIdx.x >> 5) * 64;
    const int NK = H / 64;

    int srow[4], slc[4];
    #pragma unroll
    for (int u = 0; u < 4; ++u) {
        int s = u * 256 + tid;
        srow[u] = s >> 3;
        slc[u]  = (s & 7) ^ (srow[u] & 7);
    }

    #define OSTAGE(IT, NB)                                                    \
        _Pragma("unroll")                                                     \
        for (int u = 0; u < 4; ++u)                                           \
            g2l16(A + (size_t)(m0 + srow[u]) * H + (IT) * 64 + slc[u] * 8,    \
                  &Abuf[NB][(u * 256 + w * 64) * 8]);                         \
        _Pragma("unroll")                                                     \
        for (int u = 0; u < 2; ++u)                                           \
            g2l16(BT + (size_t)(n0 + srow[u]) * H + (IT) * 64 + slc[u] * 8,   \
                  &Bbuf[NB][(u * 256 + w * 64) * 8]);

    OSTAGE(0, 0)

    f32x4 acc[4][2];
    #pragma unroll
    for (int i = 0; i < 4; ++i)
        #pragma unroll
        for (int j = 0; j < 2; ++j) acc[i][j] = (f32x4){0.f, 0.f, 0.f, 0.f};

    for (int it = 0; it < NK; ++it) {
        const int cur = it & 1;
        __syncthreads();
        if (it + 1 < NK) { OSTAGE(it + 1, cur ^ 1) }

        const u16* Ac = Abuf[cur];
        const u16* Bc = Bbuf[cur];
        #pragma unroll
        for (int kc = 0; kc < 2; ++kc) {
            const int ch = kc * 4 + quad;
            short8 af[4], bf[2];
            #pragma unroll
            for (int mi = 0; mi < 4; ++mi) {
                int row = wm + mi * 16 + l15;
                af[mi] = *(const short8*)&Ac[row * 64 + (ch ^ (row & 7)) * 8];
            }
            #pragma unroll
            for (int ni = 0; ni < 2; ++ni) {
                int row = wn + ni * 16 + l15;
                bf[ni] = *(const short8*)&Bc[row * 64 + (ch ^ (row & 7)) * 8];
            }
            #pragma unroll
            for (int mi = 0; mi < 4; ++mi)
                #pragma unroll
                for (int ni = 0; ni < 2; ++ni)
                    acc[mi][ni] = __builtin_amdgcn_mfma_f32_16x16x32_bf16(
                        af[mi], bf[ni], acc[mi][ni], 0, 0, 0);
        }
    }
    #undef OSTAGE

    #pragma unroll
    for (int mi = 0; mi < 4; ++mi) {
        const int mbase = m0 + wm + mi * 16 + quad * 4;
        #pragma unroll
        for (int ni = 0; ni < 2; ++ni) {
            const int col = n0 + wn + ni * 16 + l15;
            const float bias = bo[col];
            #pragma unroll
            for (int r = 0; r < 4; ++r)
                out[(size_t)(mbase + r) * H + col] = acc[mi][ni][r] + bias;
        }
    }
}

// ---------------------------------------------------------------------------
// Flash attention, TRANSPOSED-S formulation, round-5 loop structure +
// vmcnt(8) counted wait. Round-22: REVERT of round-21's serial-chain diet
// (mask-skip + QK 2-chain split regressed 45.0->48.2: VALUBusy 42->48,
// MfmaUtil 31->28.5 — at 3 waves/SIMD the 4-deep MFMA chain was already
// TLP-hidden; the split only added 16 v_add + 16 live VGPRs + a branch).
// This is the best-measured attn configuration (45.0 us, VGPR 72):
// triple-buffer staging, T4 counted vmcnt(8) (drain STAGE(jt) exactly,
// leave STAGE(jt+1)'s 8 loads in flight), single barrier per iter,
// half-up+v_perm P-pack, permlane32_swap exchange, MFMA-pipe row-sum,
// s_setprio around MFMA clusters, mask->mt LDS table, Q from QT layout.
// ---------------------------------------------------------------------------
__global__ __launch_bounds__(256, 3) void attn_mfma_kernel(
    const u16* __restrict__ QT, const u16* __restrict__ K,
    const u16* __restrict__ VT, const float* __restrict__ mask,
    u16* __restrict__ ctx)
{
    // u16 layout: [0,24576) = 3 x (K 4096 | V 4096) staging buffers
    //             [24576,26624) = mt table (2048 bf16)
    __shared__ alignas(16) u16 smem[26624];   // 53248 B

    const int tid  = threadIdx.x;
    const int w    = tid >> 6;
    const int lane = tid & 63;
    const int l31  = lane & 31;
    const int h5   = lane >> 5;
    const int rh   = w & 1;   // row-half
    const int kh   = w >> 1;  // key-half
    const int bid = blockIdx.x;
    const int bn = bid % 24;              // XCD-local head
    const int q0 = (bid / 24) * 64;
    const int b = bn / NH, hh = bn % NH;
    const int NT = S / 64;                // 32

    // Q B-fragments from QT[b,h,d,s]: lane n = l31 = qrow, k = kc*16+h5*8+j
    short8 qa[4];
    {
        const u16* Qp = QT + (size_t)bn * HD * S + (q0 + rh * 32 + l31);
        #pragma unroll
        for (int kc = 0; kc < 4; ++kc)
            #pragma unroll
            for (int j = 0; j < 8; ++j)
                qa[kc][j] = (short)Qp[(size_t)(kc * 16 + h5 * 8 + j) * S];
    }

    // constant B-frag for the mask MFMA: B[k=0][n]=1
    short8 oneb = {};
    if (h5 == 0) oneb[0] = (short)0x3F80;   // bf16 1.0

    // all-ones A-frag for the l row-sum MFMA (A[m][k] = 1 for all m,k)
    short8 onesa;
    #pragma unroll
    for (int i = 0; i < 8; ++i) onesa[i] = (short)0x3F80;

    const u16* Kg = K + (size_t)bn * S * HD;
    const u16* Vg = VT + (size_t)bn * HD * S;
    const float* mrow = mask + (size_t)b * S;
    u16* const mtl = smem + 24576;

    // ---- prologue: mask -> mt bf16 LDS table (2048 entries) ----
    {
        const int i0 = tid * 8;
        float4 ma = *(const float4*)(mrow + i0);
        float4 mb = *(const float4*)(mrow + i0 + 4);
        const float c = -10000.0f * LOG2E;
        ushort4 p0, p1;
        p0.x = f2bf((1.0f - ma.x) * c); p0.y = f2bf((1.0f - ma.y) * c);
        p0.z = f2bf((1.0f - ma.z) * c); p0.w = f2bf((1.0f - ma.w) * c);
        p1.x = f2bf((1.0f - mb.x) * c); p1.y = f2bf((1.0f - mb.y) * c);
        p1.z = f2bf((1.0f - mb.z) * c); p1.w = f2bf((1.0f - mb.w) * c);
        *(ushort4*)(mtl + i0)     = p0;
        *(ushort4*)(mtl + i0 + 4) = p1;
    }

    int srow[2], slc[2];
    #pragma unroll
    for (int u = 0; u < 2; ++u) {
        int s = u * 256 + tid;
        srow[u] = s >> 3;
        slc[u]  = (s & 7) ^ (srow[u] & 7);
    }

    #define STAGE(JT, NB)                                                     \
        _Pragma("unroll")                                                     \
        for (int u = 0; u < 2; ++u) {                                         \
            g2l16(Kg + (size_t)((JT) * 64 + srow[u]) * HD + slc[u] * 8,       \
                  smem + (NB) * 8192 + (u * 256 + w * 64) * 8);               \
            g2l16(Vg + (size_t)srow[u] * S + (JT) * 64 + slc[u] * 8,          \
                  smem + (NB) * 8192 + 4096 + (u * 256 + w * 64) * 8);        \
        }

    // drain Q/mask loads + publish mt ds_writes, THEN start counted staging
    asm volatile("s_waitcnt vmcnt(0) lgkmcnt(0)" ::: "memory");
    STAGE(0, 0)
    STAGE(1, 1)

    const f32x16 zc = zero16();           // hoisted C=0 for the mask MFMA
    f32x16 o0 = zero16(), o1 = zero16(), lac = zero16();
    const u32 psel = 0x07060302u;         // v_perm sel: [S0.hi16 | S1.hi16]

    int cur = 0;                          // jt % 3
    for (int jt = 0; jt < NT; ++jt) {
        // T4 counted wait: drain STAGE(jt)'s 8 loads exactly; leave
        // STAGE(jt+1)'s 8 fully in flight.
        if (jt < NT - 1) asm volatile("s_waitcnt vmcnt(8)" ::: "memory");
        else             asm volatile("s_waitcnt vmcnt(0)" ::: "memory");
        __builtin_amdgcn_s_barrier();
        // buffer (jt+2)%3 == (jt-1)%3 was fully consumed by compute(jt-1)
        // before the barrier above -> safe to DMA into it now.
        if (jt + 2 < NT) {
            const int nb = (cur >= 1) ? cur - 1 : cur + 2;
            STAGE(jt + 2, nb)
        }

        const u16* Kc = smem + cur * 8192;
        const u16* Vc = smem + cur * 8192 + 4096;

        // mask as MFMA: sc^T[key][qrow] = mt[key]  (mt from LDS table)
        const u16 mtv = mtl[jt * 64 + kh * 32 + l31];
        short8 mta = {};
        if (h5 == 0) mta[0] = (short)mtv;

        __builtin_amdgcn_s_setprio(1);
        f32x16 sc = __builtin_amdgcn_mfma_f32_32x32x16_bf16(
            mta, oneb, zc, 0, 0, 0);

        // S^T += K . Q^T  (A = K-frag m=key, B = Q-frag n=qrow)
        {
            const int krow = kh * 32 + l31;
            const int sw = krow & 7;
            #pragma unroll
            for (int kc = 0; kc < 4; ++kc) {
                const short8 kb =
                    *(const short8*)&Kc[krow * 64 + ((kc * 2 + h5) ^ sw) * 8];
                sc = __builtin_amdgcn_mfma_f32_32x32x16_bf16(kb, qa[kc], sc, 0, 0, 0);
            }
        }
        __builtin_amdgcn_s_setprio(0);

        // V^T A-frags (m = dim), read while exp burst runs
        short8 va[2][2];
        #pragma unroll
        for (int nt = 0; nt < 2; ++nt) {
            const int vrow = nt * 32 + l31;
            const int sw = vrow & 7;
            va[nt][0] = *(const short8*)&Vc[vrow * 64 + ((kh * 4 + h5) ^ sw) * 8];
            va[nt][1] = *(const short8*)&Vc[vrow * 64 + ((kh * 4 + 2 + h5) ^ sw) * 8];
        }

        // p = exp2(sc); pack bf16 pairs: round-half-up in the int domain
        // (u + 0x8000; vs RNE only exact-tie differences, unbiased),
        // then one v_perm_b32 per pair grabs both hi-16s.
        // reg r -> key (r&3)+8*(r>>2)+4*h5, so d[i] = keys (2i,2i+1).
        u32 t[16];
        #pragma unroll
        for (int r = 0; r < 16; ++r) {
            union { float f; u32 u; } c;
            c.f = __builtin_amdgcn_exp2f(sc[r]);
            t[r] = c.u + 0x8000u;
        }
        u32 d[8];
        #pragma unroll
        for (int i = 0; i < 8; ++i)
            asm("v_perm_b32 %0, %1, %2, %3"
                : "=v"(d[i]) : "v"(t[2 * i + 1]), "v"(t[2 * i]), "s"(psel));

        // half-wave exchange via permlane32_swap: after swap(a,b)
        //   a = [a.lo | b.lo^]  (lanes 0-31 keep a.lo; 32-63 get b's lanes0-31)
        //   b = [a.hi_v | b.hi] (lanes 0-31 get a's lanes32-63; 32-63 keep b)
        // which are exactly fragment words (W0,W2)/(W1,W3) of P^T.
        u32 a0 = d[0], b0 = d[2];
        u32 a1 = d[1], b1 = d[3];
        u32 a2 = d[4], b2 = d[6];
        u32 a3 = d[5], b3 = d[7];
        asm("v_permlane32_swap_b32 %0, %1" : "+v"(a0), "+v"(b0));
        asm("v_permlane32_swap_b32 %0, %1" : "+v"(a1), "+v"(b1));
        asm("v_permlane32_swap_b32 %0, %1" : "+v"(a2), "+v"(b2));
        asm("v_permlane32_swap_b32 %0, %1" : "+v"(a3), "+v"(b3));

        pk4 f0, f1;
        f0.u = make_uint4(a0, a1, b0, b1);   // keys 0..15 of this tile-half
        f1.u = make_uint4(a2, a3, b2, b3);   // keys 16..31

        // O^T += V^T . P^T ; l += ones . P^T (row-sum on the MFMA pipe)
        __builtin_amdgcn_s_setprio(1);
        o0 = __builtin_amdgcn_mfma_f32_32x32x16_bf16(va[0][0], f0.s, o0, 0, 0, 0);
        o0 = __builtin_amdgcn_mfma_f32_32x32x16_bf16(va[0][1], f1.s, o0, 0, 0, 0);
        o1 = __builtin_amdgcn_mfma_f32_32x32x16_bf16(va[1][0], f0.s, o1, 0, 0, 0);
        o1 = __builtin_amdgcn_mfma_f32_32x32x16_bf16(va[1][1], f1.s, o1, 0, 0, 0);
        lac = __builtin_amdgcn_mfma_f32_32x32x16_bf16(onesa, f0.s, lac, 0, 0, 0);
        lac = __builtin_amdgcn_mfma_f32_32x32x16_bf16(onesa, f1.s, lac, 0, 0, 0);
        __builtin_amdgcn_s_setprio(0);

        cur = (cur == 2) ? 0 : cur + 1;
    }
    #undef STAGE

    // every reg of lac == sum over this wave's keys of p, for qrow = l31
    // (identical across both h5 halves -> no cross-half exchange needed)
    float l_acc = lac[0];

    __syncthreads();   // staging fully consumed -> reuse smem for combine
    float* cb = (float*)smem;             // bytes [0,16384): [r(32)][rh*64+lane]
    float* lb = (float*)(smem + 8192);    // bytes [16384,16640): [rh][qrow]

    if (kh == 1) {
        #pragma unroll
        for (int r = 0; r < 16; ++r) {
            cb[r * 128 + rh * 64 + lane]        = o0[r];
            cb[(16 + r) * 128 + rh * 64 + lane] = o1[r];
        }
        if (h5 == 0) lb[rh * 32 + l31] = l_acc;
    }
    __syncthreads();
    if (kh == 0) {
        float lt = l_acc + lb[rh * 32 + l31];
        float inv = 1.0f / lt;
        const int s = q0 + rh * 32 + l31;
        u16* dst = ctx + ((size_t)b * S + s) * H + hh * 64;
        // dims: o0 reg r -> d = (r&3) + 8*(r>>2) + 4*h5 ; o1 -> +32
        #pragma unroll
        for (int g = 0; g < 4; ++g) {
            ushort4 pk0, pk1;
            pk0.x = f2bf((o0[4 * g + 0] + cb[(4 * g + 0) * 128 + rh * 64 + lane]) * inv);
            pk0.y = f2bf((o0[4 * g + 1] + cb[(4 * g + 1) * 128 + rh * 64 + lane]) * inv);
            pk0.z = f2bf((o0[4 * g + 2] + cb[(4 * g + 2) * 128 + rh * 64 + lane]) * inv);
            pk0.w = f2bf((o0[4 * g + 3] + cb[(4 * g + 3) * 128 + rh * 64 + lane]) * inv);
            *(ushort4*)(dst + 8 * g + 4 * h5) = pk0;
            pk1.x = f2bf((o1[4 * g + 0] + cb[(16 + 4 * g + 0) * 128 + rh * 64 + lane]) * inv);
            pk1.y = f2bf((o1[4 * g + 1] + cb[(16 + 4 * g + 1) * 128 + rh * 64 + lane]) * inv);
            pk1.z = f2bf((o1[4 * g + 2] + cb[(16 + 4 * g + 2) * 128 + rh * 64 + lane]) * inv);
            pk1.w = f2bf((o1[4 * g + 3] + cb[(16 + 4 * g + 3) * 128 + rh * 64 + lane]) * inv);
            *(ushort4*)(dst + 32 + 8 * g + 4 * h5) = pk1;
        }
    }
}

// ---------------------------------------------------------------------------
extern "C" void kernel_launch(void* const* d_in, const int* in_sizes, int n_in,
                              void* d_out, int out_size, void* d_ws, size_t ws_size,
                              hipStream_t stream)
{
    const float* hs   = (const float*)d_in[0];
    const float* mask = (const float*)d_in[1];
    const float* Wq   = (const float*)d_in[2];
    const float* bq   = (const float*)d_in[3];
    const float* Wk   = (const float*)d_in[4];
    const float* bk   = (const float*)d_in[5];
    const float* Wv   = (const float*)d_in[6];
    const float* bv   = (const float*)d_in[7];
    const float* Wo   = (const float*)d_in[8];
    const float* bo   = (const float*)d_in[9];
    const float* cosp = (const float*)d_in[10];
    const float* sinp = (const float*)d_in[11];
    float* out = (float*)d_out;

    const size_t per = (size_t)B * NH * S * HD;   // 3,145,728
    u16* ws    = (u16*)d_ws;
    u16* hsb   = ws;                              // bf16 hidden  [BS,H]
    u16* WTqkv = hsb + per;                       // bf16 [2304,768] (Q/K rotated)
    u16* WTo   = WTqkv + (size_t)3 * H * H;       // bf16 [768,768]
    u16* QTb   = WTo + (size_t)H * H;             // bf16 [B,NH,HD,S] (transposed)
    u16* Kb    = QTb + per;                       // bf16 [B,NH,S,HD]
    u16* VT    = Kb + per;                        // bf16 [B,NH,HD,S]
    u16* ctxb  = VT + per;                        // bf16 [BS,H]
    float* bqk2 = (float*)(ctxb + per);           // rotated biases [2*H]

    prep_kernel<<<576 + (BS * H) / 2048, 256, 0, stream>>>(
        hs, Wq, Wk, Wv, Wo, bq, bk, cosp, sinp, hsb, WTqkv, WTo, bqk2);

    gemm_qkv_kernel<<<(BS / 128) * (2304 / 128), 256, 0, stream>>>(
        hsb, WTqkv, bqk2, bv, QTb, Kb, VT);

    attn_mfma_kernel<<<(S / 64) * (B * NH), 256, 0, stream>>>(
        QTb, Kb, VT, mask, ctxb);

    gemm_out_kernel<<<(BS / 128) * (H / 64), 256, 0, stream>>>(
        ctxb, WTo, bo, out);
}

// Round 12
// 169.117 us; speedup vs baseline: 1.0770x; 1.0770x over previous
//
#include <hip/hip_runtime.h>

#define B 2
#define S 2048
#define H 768
#define NH 12
#define HD 64
#define BS (B * S)
#define LOG2E 1.4426950408889634f

typedef unsigned short u16;
typedef unsigned int u32;
typedef short short8 __attribute__((ext_vector_type(8)));
typedef float f32x4 __attribute__((ext_vector_type(4)));
typedef float f32x16 __attribute__((ext_vector_type(16)));

// fp32 -> bf16 round-to-nearest-even
__device__ __forceinline__ u16 f2bf(float f) {
    union { float f; unsigned u; } c; c.f = f;
    unsigned u = c.u + 0x7FFFu + ((c.u >> 16) & 1u);
    return (u16)(u >> 16);
}
__device__ __forceinline__ float bf2f(u16 h) {
    union { unsigned u; float f; } c; c.u = ((unsigned)h) << 16;
    return c.f;
}
__device__ __forceinline__ f32x16 zero16() {
    f32x16 v;
    #pragma unroll
    for (int i = 0; i < 16; ++i) v[i] = 0.f;
    return v;
}
union pk4 { uint4 u; short8 s; };

// async global->LDS DMA, 16 B per lane; lds dest = wave-uniform base + lane*16
__device__ __forceinline__ void g2l16(const u16* g, u16* l) {
    __builtin_amdgcn_global_load_lds(
        (const __attribute__((address_space(1))) void*)g,
        (__attribute__((address_space(3))) void*)l, 16, 0, 0);
}

// ---------------------------------------------------------------------------
// Merged prep: blocks [0,576) transpose+convert weights (RoPE folded into
// Wq/Wk per the reference's head-indexed-table quirk; Q also folds
// 0.125*log2e); blocks [576,2112) convert hidden_states fp32->bf16.
// ---------------------------------------------------------------------------
__global__ __launch_bounds__(256) void prep_kernel(
    const float* __restrict__ hs,
    const float* __restrict__ Wq, const float* __restrict__ Wk,
    const float* __restrict__ Wv, const float* __restrict__ Wo,
    const float* __restrict__ bq, const float* __restrict__ bk,
    const float* __restrict__ cosp, const float* __restrict__ sinp,
    u16* __restrict__ hsb, u16* __restrict__ WTqkv, u16* __restrict__ WTo,
    float* __restrict__ bqk2)
{
    __shared__ float Lt[64 * 65];
    const int bid = blockIdx.x;
    const int t = threadIdx.x;

    if (bid >= 576) {                       // ---- hidden_states convert ----
        size_t i = ((size_t)(bid - 576) * 256 + t) * 8;
        float4 a = *(const float4*)(hs + i);
        float4 b = *(const float4*)(hs + i + 4);
        short8 p;
        p[0] = (short)f2bf(a.x); p[1] = (short)f2bf(a.y);
        p[2] = (short)f2bf(a.z); p[3] = (short)f2bf(a.w);
        p[4] = (short)f2bf(b.x); p[5] = (short)f2bf(b.y);
        p[6] = (short)f2bf(b.z); p[7] = (short)f2bf(b.w);
        *(short8*)(hsb + i) = p;
        return;
    }

    // ---- weight transpose (+RoPE fold for z<2) ----
    const int z   = bid / 144;
    const int rem = bid - z * 144;
    const int k0 = (rem / 12) * 64, n0 = (rem % 12) * 64;
    const float* W = (z == 0) ? Wq : (z == 1) ? Wk : (z == 2) ? Wv : Wo;
    u16* D = (z == 3) ? WTo : (WTqkv + (size_t)z * H * H);
    const int head = n0 >> 6;
    const float scl = (z == 0) ? (0.125f * LOG2E) : 1.0f;

    if (z < 2 && rem / 12 == 0 && t < 64) {   // rotated bias, once per col-tile
        const float* bs = (z == 0) ? bq : bk;
        int d = t;
        int pd = (d < 32) ? (2 * d + 1) : (2 * (d - 32));
        float sv = ((d < 32) ? -1.f : 1.f) * sinp[head * HD + d];
        float cv = cosp[head * HD + d];
        bqk2[z * H + n0 + d] = scl * (cv * bs[n0 + d] + sv * bs[n0 + pd]);
    }

    #pragma unroll
    for (int u = 0; u < 4; ++u) {
        int f = t + u * 256;
        int r = f >> 4, c4 = (f & 15) * 4;
        float4 w = *(const float4*)(W + (size_t)(k0 + r) * H + n0 + c4);
        Lt[r * 65 + c4 + 0] = w.x; Lt[r * 65 + c4 + 1] = w.y;
        Lt[r * 65 + c4 + 2] = w.z; Lt[r * 65 + c4 + 3] = w.w;
    }
    __syncthreads();
    #pragma unroll
    for (int u = 0; u < 4; ++u) {
        int f = t + u * 256;
        int n = f >> 4, k4 = (f & 15) * 4;
        ushort4 p;
        if (z < 2) {
            int pn = (n < 32) ? (2 * n + 1) : (2 * (n - 32));
            float cv = scl * cosp[head * HD + n];
            float sv = scl * ((n < 32) ? -1.f : 1.f) * sinp[head * HD + n];
            p.x = f2bf(cv * Lt[(k4 + 0) * 65 + n] + sv * Lt[(k4 + 0) * 65 + pn]);
            p.y = f2bf(cv * Lt[(k4 + 1) * 65 + n] + sv * Lt[(k4 + 1) * 65 + pn]);
            p.z = f2bf(cv * Lt[(k4 + 2) * 65 + n] + sv * Lt[(k4 + 2) * 65 + pn]);
            p.w = f2bf(cv * Lt[(k4 + 3) * 65 + n] + sv * Lt[(k4 + 3) * 65 + pn]);
        } else {
            p.x = f2bf(Lt[(k4 + 0) * 65 + n]);
            p.y = f2bf(Lt[(k4 + 1) * 65 + n]);
            p.z = f2bf(Lt[(k4 + 2) * 65 + n]);
            p.w = f2bf(Lt[(k4 + 3) * 65 + n]);
        }
        *(ushort4*)(D + (size_t)(n0 + n) * H + k0 + k4) = p;
    }
}

// ---------------------------------------------------------------------------
// Fused QKV GEMM. Round-23 retile: profile showed gemm_qkv at ~51 us with
// MfmaUtil 10%, Occupancy 13%, HBM 10% — latency-bound at 2.25 blocks/CU
// (grid 576) with a 64 KB LDS cap of 2/CU. Retiled 128x128 -> 128x64
// (gemm_out's proven loop): LDS 48 KB -> 3 blocks/CU, grid 1152 -> 4.5
// blocks/CU (2x TLP). n-tile 64 = one head: epilogue 'which' branch is now
// block-uniform. Per-output math bit-identical (same K-order, fragments).
// Q stored TRANSPOSED ([b,h,d,s]); V transposed; K [b,h,s,d] scalar stores.
// ---------------------------------------------------------------------------
__global__ __launch_bounds__(256) void gemm_qkv_kernel(
    const u16* __restrict__ A, const u16* __restrict__ BT,
    const float* __restrict__ bqk2, const float* __restrict__ bv,
    u16* __restrict__ QTb, u16* __restrict__ Kb, u16* __restrict__ VT)
{
    __shared__ alignas(16) u16 Abuf[2][128 * 64];
    __shared__ alignas(16) u16 Bbuf[2][64 * 64];

    const int tid  = threadIdx.x;
    const int w    = tid >> 6;
    const int lane = tid & 63;
    const int quad = lane >> 4;
    const int l15  = lane & 15;
    const int wm = (w & 1) * 64, wn = (w >> 1) * 32;
    const int m0 = (blockIdx.x & 31) * 128;   // XCD-local m-slice
    const int n0 = (blockIdx.x >> 5) * 64;    // 0..35 -> col 0..2240
    const int NK = H / 64;   // 12

    int srow[4], slc[4];
    #pragma unroll
    for (int u = 0; u < 4; ++u) {
        int s = u * 256 + tid;
        srow[u] = s >> 3;
        slc[u]  = (s & 7) ^ (srow[u] & 7);
    }

    #define QSTAGE(IT, NB)                                                    \
        _Pragma("unroll")                                                     \
        for (int u = 0; u < 4; ++u)                                           \
            g2l16(A + (size_t)(m0 + srow[u]) * H + (IT) * 64 + slc[u] * 8,    \
                  &Abuf[NB][(u * 256 + w * 64) * 8]);                         \
        _Pragma("unroll")                                                     \
        for (int u = 0; u < 2; ++u)                                           \
            g2l16(BT + (size_t)(n0 + srow[u]) * H + (IT) * 64 + slc[u] * 8,   \
                  &Bbuf[NB][(u * 256 + w * 64) * 8]);

    QSTAGE(0, 0)

    f32x4 acc[4][2];
    #pragma unroll
    for (int i = 0; i < 4; ++i)
        #pragma unroll
        for (int j = 0; j < 2; ++j) acc[i][j] = (f32x4){0.f, 0.f, 0.f, 0.f};

    for (int it = 0; it < NK; ++it) {
        const int cur = it & 1;
        __syncthreads();                       // drains DMA for buffer cur
        if (it + 1 < NK) { QSTAGE(it + 1, cur ^ 1) }

        const u16* Ac = Abuf[cur];
        const u16* Bc = Bbuf[cur];
        #pragma unroll
        for (int kc = 0; kc < 2; ++kc) {
            const int ch = kc * 4 + quad;
            short8 af[4], bf[2];
            #pragma unroll
            for (int mi = 0; mi < 4; ++mi) {
                int row = wm + mi * 16 + l15;
                af[mi] = *(const short8*)&Ac[row * 64 + (ch ^ (row & 7)) * 8];
            }
            #pragma unroll
            for (int ni = 0; ni < 2; ++ni) {
                int row = wn + ni * 16 + l15;
                bf[ni] = *(const short8*)&Bc[row * 64 + (ch ^ (row & 7)) * 8];
            }
            #pragma unroll
            for (int mi = 0; mi < 4; ++mi)
                #pragma unroll
                for (int ni = 0; ni < 2; ++ni)
                    acc[mi][ni] = __builtin_amdgcn_mfma_f32_16x16x32_bf16(
                        af[mi], bf[ni], acc[mi][ni], 0, 0, 0);
        }
    }
    #undef QSTAGE

    const int which = n0 / H;                 // block-uniform: 0=Q, 1=K, 2=V
    #pragma unroll
    for (int mi = 0; mi < 4; ++mi) {
        const int mbase = m0 + wm + mi * 16 + quad * 4;
        const int b_ = mbase >> 11, s = mbase & (S - 1);   // 4 rows same b
        #pragma unroll
        for (int ni = 0; ni < 2; ++ni) {
            const int col = n0 + wn + ni * 16 + l15;      // 0..2303
            const int c = col - which * H;
            const int h = c >> 6, d = c & 63;
            if (which != 1) {
                // Q (transposed) and V (transposed): vector store
                const float bias = (which == 2) ? bv[c] : bqk2[c];
                u16* dstT = (which == 2) ? VT : QTb;
                ushort4 pk;
                pk.x = f2bf(acc[mi][ni][0] + bias);
                pk.y = f2bf(acc[mi][ni][1] + bias);
                pk.z = f2bf(acc[mi][ni][2] + bias);
                pk.w = f2bf(acc[mi][ni][3] + bias);
                *(ushort4*)&dstT[(((size_t)b_ * NH + h) * HD + d) * S + s] = pk;
            } else {
                const float bias = bqk2[H + c];   // rotated (+scaled) K bias
                #pragma unroll
                for (int r = 0; r < 4; ++r) {
                    int m = mbase + r;
                    int bb = m >> 11, ss = m & (S - 1);
                    Kb[(((size_t)bb * NH + h) * S + ss) * HD + d] =
                        f2bf(acc[mi][ni][r] + bias);
                }
            }
        }
    }
}

// ---------------------------------------------------------------------------
// Output projection: out[4096,768] fp32 = ctxb @ WTo^T + bo. 128x64 tile,
// DMA double-buffered, XOR-swizzled LDS, m-block = bid % 32 (XCD-local).
// ---------------------------------------------------------------------------
__global__ __launch_bounds__(256) void gemm_out_kernel(
    const u16* __restrict__ A, const u16* __restrict__ BT,
    const float* __restrict__ bo, float* __restrict__ out)
{
    __shared__ alignas(16) u16 Abuf[2][128 * 64];
    __shared__ alignas(16) u16 Bbuf[2][64 * 64];

    const int tid  = threadIdx.x;
    const int w    = tid >> 6;
    const int lane = tid & 63;
    const int quad = lane >> 4;
    const int l15  = lane & 15;
    const int wm = (w & 1) * 64, wn = (w >> 1) * 32;
    const int m0 = (blockIdx.x & 31) * 128;   // XCD-local m-slice
    const int n0 = (blockIdx.x >> 5) * 64;
    const int NK = H / 64;

    int srow[4], slc[4];
    #pragma unroll
    for (int u = 0; u < 4; ++u) {
        int s = u * 256 + tid;
        srow[u] = s >> 3;
        slc[u]  = (s & 7) ^ (srow[u] & 7);
    }

    #define OSTAGE(IT, NB)                                                    \
        _Pragma("unroll")                                                     \
        for (int u = 0; u < 4; ++u)                                           \
            g2l16(A + (size_t)(m0 + srow[u]) * H + (IT) * 64 + slc[u] * 8,    \
                  &Abuf[NB][(u * 256 + w * 64) * 8]);                         \
        _Pragma("unroll")                                                     \
        for (int u = 0; u < 2; ++u)                                           \
            g2l16(BT + (size_t)(n0 + srow[u]) * H + (IT) * 64 + slc[u] * 8,   \
                  &Bbuf[NB][(u * 256 + w * 64) * 8]);

    OSTAGE(0, 0)

    f32x4 acc[4][2];
    #pragma unroll
    for (int i = 0; i < 4; ++i)
        #pragma unroll
        for (int j = 0; j < 2; ++j) acc[i][j] = (f32x4){0.f, 0.f, 0.f, 0.f};

    for (int it = 0; it < NK; ++it) {
        const int cur = it & 1;
        __syncthreads();
        if (it + 1 < NK) { OSTAGE(it + 1, cur ^ 1) }

        const u16* Ac = Abuf[cur];
        const u16* Bc = Bbuf[cur];
        #pragma unroll
        for (int kc = 0; kc < 2; ++kc) {
            const int ch = kc * 4 + quad;
            short8 af[4], bf[2];
            #pragma unroll
            for (int mi = 0; mi < 4; ++mi) {
                int row = wm + mi * 16 + l15;
                af[mi] = *(const short8*)&Ac[row * 64 + (ch ^ (row & 7)) * 8];
            }
            #pragma unroll
            for (int ni = 0; ni < 2; ++ni) {
                int row = wn + ni * 16 + l15;
                bf[ni] = *(const short8*)&Bc[row * 64 + (ch ^ (row & 7)) * 8];
            }
            #pragma unroll
            for (int mi = 0; mi < 4; ++mi)
                #pragma unroll
                for (int ni = 0; ni < 2; ++ni)
                    acc[mi][ni] = __builtin_amdgcn_mfma_f32_16x16x32_bf16(
                        af[mi], bf[ni], acc[mi][ni], 0, 0, 0);
        }
    }
    #undef OSTAGE

    #pragma unroll
    for (int mi = 0; mi < 4; ++mi) {
        const int mbase = m0 + wm + mi * 16 + quad * 4;
        #pragma unroll
        for (int ni = 0; ni < 2; ++ni) {
            const int col = n0 + wn + ni * 16 + l15;
            const float bias = bo[col];
            #pragma unroll
            for (int r = 0; r < 4; ++r)
                out[(size_t)(mbase + r) * H + col] = acc[mi][ni][r] + bias;
        }
    }
}

// ---------------------------------------------------------------------------
// Flash attention, TRANSPOSED-S formulation, round-5 loop structure +
// vmcnt(8) counted wait — the best-measured attn configuration (45.0 us,
// VGPR 72): triple-buffer staging, T4 counted vmcnt(8) (drain STAGE(jt)
// exactly, leave STAGE(jt+1)'s 8 loads in flight), single barrier per iter,
// half-up+v_perm P-pack, permlane32_swap exchange, MFMA-pipe row-sum,
// s_setprio around MFMA clusters, mask->mt LDS table, Q from QT layout.
// (T15 2-deep variants and serial-chain diets all regressed — r17/r18/r21.)
// ---------------------------------------------------------------------------
__global__ __launch_bounds__(256, 3) void attn_mfma_kernel(
    const u16* __restrict__ QT, const u16* __restrict__ K,
    const u16* __restrict__ VT, const float* __restrict__ mask,
    u16* __restrict__ ctx)
{
    // u16 layout: [0,24576) = 3 x (K 4096 | V 4096) staging buffers
    //             [24576,26624) = mt table (2048 bf16)
    __shared__ alignas(16) u16 smem[26624];   // 53248 B

    const int tid  = threadIdx.x;
    const int w    = tid >> 6;
    const int lane = tid & 63;
    const int l31  = lane & 31;
    const int h5   = lane >> 5;
    const int rh   = w & 1;   // row-half
    const int kh   = w >> 1;  // key-half
    const int bid = blockIdx.x;
    const int bn = bid % 24;              // XCD-local head
    const int q0 = (bid / 24) * 64;
    const int b = bn / NH, hh = bn % NH;
    const int NT = S / 64;                // 32

    // Q B-fragments from QT[b,h,d,s]: lane n = l31 = qrow, k = kc*16+h5*8+j
    short8 qa[4];
    {
        const u16* Qp = QT + (size_t)bn * HD * S + (q0 + rh * 32 + l31);
        #pragma unroll
        for (int kc = 0; kc < 4; ++kc)
            #pragma unroll
            for (int j = 0; j < 8; ++j)
                qa[kc][j] = (short)Qp[(size_t)(kc * 16 + h5 * 8 + j) * S];
    }

    // constant B-frag for the mask MFMA: B[k=0][n]=1
    short8 oneb = {};
    if (h5 == 0) oneb[0] = (short)0x3F80;   // bf16 1.0

    // all-ones A-frag for the l row-sum MFMA (A[m][k] = 1 for all m,k)
    short8 onesa;
    #pragma unroll
    for (int i = 0; i < 8; ++i) onesa[i] = (short)0x3F80;

    const u16* Kg = K + (size_t)bn * S * HD;
    const u16* Vg = VT + (size_t)bn * HD * S;
    const float* mrow = mask + (size_t)b * S;
    u16* const mtl = smem + 24576;

    // ---- prologue: mask -> mt bf16 LDS table (2048 entries) ----
    {
        const int i0 = tid * 8;
        float4 ma = *(const float4*)(mrow + i0);
        float4 mb = *(const float4*)(mrow + i0 + 4);
        const float c = -10000.0f * LOG2E;
        ushort4 p0, p1;
        p0.x = f2bf((1.0f - ma.x) * c); p0.y = f2bf((1.0f - ma.y) * c);
        p0.z = f2bf((1.0f - ma.z) * c); p0.w = f2bf((1.0f - ma.w) * c);
        p1.x = f2bf((1.0f - mb.x) * c); p1.y = f2bf((1.0f - mb.y) * c);
        p1.z = f2bf((1.0f - mb.z) * c); p1.w = f2bf((1.0f - mb.w) * c);
        *(ushort4*)(mtl + i0)     = p0;
        *(ushort4*)(mtl + i0 + 4) = p1;
    }

    int srow[2], slc[2];
    #pragma unroll
    for (int u = 0; u < 2; ++u) {
        int s = u * 256 + tid;
        srow[u] = s >> 3;
        slc[u]  = (s & 7) ^ (srow[u] & 7);
    }

    #define STAGE(JT, NB)                                                     \
        _Pragma("unroll")                                                     \
        for (int u = 0; u < 2; ++u) {                                         \
            g2l16(Kg + (size_t)((JT) * 64 + srow[u]) * HD + slc[u] * 8,       \
                  smem + (NB) * 8192 + (u * 256 + w * 64) * 8);               \
            g2l16(Vg + (size_t)srow[u] * S + (JT) * 64 + slc[u] * 8,          \
                  smem + (NB) * 8192 + 4096 + (u * 256 + w * 64) * 8);        \
        }

    // drain Q/mask loads + publish mt ds_writes, THEN start counted staging
    asm volatile("s_waitcnt vmcnt(0) lgkmcnt(0)" ::: "memory");
    STAGE(0, 0)
    STAGE(1, 1)

    const f32x16 zc = zero16();           // hoisted C=0 for the mask MFMA
    f32x16 o0 = zero16(), o1 = zero16(), lac = zero16();
    const u32 psel = 0x07060302u;         // v_perm sel: [S0.hi16 | S1.hi16]

    int cur = 0;                          // jt % 3
    for (int jt = 0; jt < NT; ++jt) {
        // T4 counted wait: drain STAGE(jt)'s 8 loads exactly; leave
        // STAGE(jt+1)'s 8 fully in flight.
        if (jt < NT - 1) asm volatile("s_waitcnt vmcnt(8)" ::: "memory");
        else             asm volatile("s_waitcnt vmcnt(0)" ::: "memory");
        __builtin_amdgcn_s_barrier();
        // buffer (jt+2)%3 == (jt-1)%3 was fully consumed by compute(jt-1)
        // before the barrier above -> safe to DMA into it now.
        if (jt + 2 < NT) {
            const int nb = (cur >= 1) ? cur - 1 : cur + 2;
            STAGE(jt + 2, nb)
        }

        const u16* Kc = smem + cur * 8192;
        const u16* Vc = smem + cur * 8192 + 4096;

        // mask as MFMA: sc^T[key][qrow] = mt[key]  (mt from LDS table)
        const u16 mtv = mtl[jt * 64 + kh * 32 + l31];
        short8 mta = {};
        if (h5 == 0) mta[0] = (short)mtv;

        __builtin_amdgcn_s_setprio(1);
        f32x16 sc = __builtin_amdgcn_mfma_f32_32x32x16_bf16(
            mta, oneb, zc, 0, 0, 0);

        // S^T += K . Q^T  (A = K-frag m=key, B = Q-frag n=qrow)
        {
            const int krow = kh * 32 + l31;
            const int sw = krow & 7;
            #pragma unroll
            for (int kc = 0; kc < 4; ++kc) {
                const short8 kb =
                    *(const short8*)&Kc[krow * 64 + ((kc * 2 + h5) ^ sw) * 8];
                sc = __builtin_amdgcn_mfma_f32_32x32x16_bf16(kb, qa[kc], sc, 0, 0, 0);
            }
        }
        __builtin_amdgcn_s_setprio(0);

        // V^T A-frags (m = dim), read while exp burst runs
        short8 va[2][2];
        #pragma unroll
        for (int nt = 0; nt < 2; ++nt) {
            const int vrow = nt * 32 + l31;
            const int sw = vrow & 7;
            va[nt][0] = *(const short8*)&Vc[vrow * 64 + ((kh * 4 + h5) ^ sw) * 8];
            va[nt][1] = *(const short8*)&Vc[vrow * 64 + ((kh * 4 + 2 + h5) ^ sw) * 8];
        }

        // p = exp2(sc); pack bf16 pairs: round-half-up in the int domain
        // (u + 0x8000; vs RNE only exact-tie differences, unbiased),
        // then one v_perm_b32 per pair grabs both hi-16s.
        // reg r -> key (r&3)+8*(r>>2)+4*h5, so d[i] = keys (2i,2i+1).
        u32 t[16];
        #pragma unroll
        for (int r = 0; r < 16; ++r) {
            union { float f; u32 u; } c;
            c.f = __builtin_amdgcn_exp2f(sc[r]);
            t[r] = c.u + 0x8000u;
        }
        u32 d[8];
        #pragma unroll
        for (int i = 0; i < 8; ++i)
            asm("v_perm_b32 %0, %1, %2, %3"
                : "=v"(d[i]) : "v"(t[2 * i + 1]), "v"(t[2 * i]), "s"(psel));

        // half-wave exchange via permlane32_swap: after swap(a,b)
        //   a = [a.lo | b.lo^]  (lanes 0-31 keep a.lo; 32-63 get b's lanes0-31)
        //   b = [a.hi_v | b.hi] (lanes 0-31 get a's lanes32-63; 32-63 keep b)
        // which are exactly fragment words (W0,W2)/(W1,W3) of P^T.
        u32 a0 = d[0], b0 = d[2];
        u32 a1 = d[1], b1 = d[3];
        u32 a2 = d[4], b2 = d[6];
        u32 a3 = d[5], b3 = d[7];
        asm("v_permlane32_swap_b32 %0, %1" : "+v"(a0), "+v"(b0));
        asm("v_permlane32_swap_b32 %0, %1" : "+v"(a1), "+v"(b1));
        asm("v_permlane32_swap_b32 %0, %1" : "+v"(a2), "+v"(b2));
        asm("v_permlane32_swap_b32 %0, %1" : "+v"(a3), "+v"(b3));

        pk4 f0, f1;
        f0.u = make_uint4(a0, a1, b0, b1);   // keys 0..15 of this tile-half
        f1.u = make_uint4(a2, a3, b2, b3);   // keys 16..31

        // O^T += V^T . P^T ; l += ones . P^T (row-sum on the MFMA pipe)
        __builtin_amdgcn_s_setprio(1);
        o0 = __builtin_amdgcn_mfma_f32_32x32x16_bf16(va[0][0], f0.s, o0, 0, 0, 0);
        o0 = __builtin_amdgcn_mfma_f32_32x32x16_bf16(va[0][1], f1.s, o0, 0, 0, 0);
        o1 = __builtin_amdgcn_mfma_f32_32x32x16_bf16(va[1][0], f0.s, o1, 0, 0, 0);
        o1 = __builtin_amdgcn_mfma_f32_32x32x16_bf16(va[1][1], f1.s, o1, 0, 0, 0);
        lac = __builtin_amdgcn_mfma_f32_32x32x16_bf16(onesa, f0.s, lac, 0, 0, 0);
        lac = __builtin_amdgcn_mfma_f32_32x32x16_bf16(onesa, f1.s, lac, 0, 0, 0);
        __builtin_amdgcn_s_setprio(0);

        cur = (cur == 2) ? 0 : cur + 1;
    }
    #undef STAGE

    // every reg of lac == sum over this wave's keys of p, for qrow = l31
    // (identical across both h5 halves -> no cross-half exchange needed)
    float l_acc = lac[0];

    __syncthreads();   // staging fully consumed -> reuse smem for combine
    float* cb = (float*)smem;             // bytes [0,16384): [r(32)][rh*64+lane]
    float* lb = (float*)(smem + 8192);    // bytes [16384,16640): [rh][qrow]

    if (kh == 1) {
        #pragma unroll
        for (int r = 0; r < 16; ++r) {
            cb[r * 128 + rh * 64 + lane]        = o0[r];
            cb[(16 + r) * 128 + rh * 64 + lane] = o1[r];
        }
        if (h5 == 0) lb[rh * 32 + l31] = l_acc;
    }
    __syncthreads();
    if (kh == 0) {
        float lt = l_acc + lb[rh * 32 + l31];
        float inv = 1.0f / lt;
        const int s = q0 + rh * 32 + l31;
        u16* dst = ctx + ((size_t)b * S + s) * H + hh * 64;
        // dims: o0 reg r -> d = (r&3) + 8*(r>>2) + 4*h5 ; o1 -> +32
        #pragma unroll
        for (int g = 0; g < 4; ++g) {
            ushort4 pk0, pk1;
            pk0.x = f2bf((o0[4 * g + 0] + cb[(4 * g + 0) * 128 + rh * 64 + lane]) * inv);
            pk0.y = f2bf((o0[4 * g + 1] + cb[(4 * g + 1) * 128 + rh * 64 + lane]) * inv);
            pk0.z = f2bf((o0[4 * g + 2] + cb[(4 * g + 2) * 128 + rh * 64 + lane]) * inv);
            pk0.w = f2bf((o0[4 * g + 3] + cb[(4 * g + 3) * 128 + rh * 64 + lane]) * inv);
            *(ushort4*)(dst + 8 * g + 4 * h5) = pk0;
            pk1.x = f2bf((o1[4 * g + 0] + cb[(16 + 4 * g + 0) * 128 + rh * 64 + lane]) * inv);
            pk1.y = f2bf((o1[4 * g + 1] + cb[(16 + 4 * g + 1) * 128 + rh * 64 + lane]) * inv);
            pk1.z = f2bf((o1[4 * g + 2] + cb[(16 + 4 * g + 2) * 128 + rh * 64 + lane]) * inv);
            pk1.w = f2bf((o1[4 * g + 3] + cb[(16 + 4 * g + 3) * 128 + rh * 64 + lane]) * inv);
            *(ushort4*)(dst + 32 + 8 * g + 4 * h5) = pk1;
        }
    }
}

// ---------------------------------------------------------------------------
extern "C" void kernel_launch(void* const* d_in, const int* in_sizes, int n_in,
                              void* d_out, int out_size, void* d_ws, size_t ws_size,
                              hipStream_t stream)
{
    const float* hs   = (const float*)d_in[0];
    const float* mask = (const float*)d_in[1];
    const float* Wq   = (const float*)d_in[2];
    const float* bq   = (const float*)d_in[3];
    const float* Wk   = (const float*)d_in[4];
    const float* bk   = (const float*)d_in[5];
    const float* Wv   = (const float*)d_in[6];
    const float* bv   = (const float*)d_in[7];
    const float* Wo   = (const float*)d_in[8];
    const float* bo   = (const float*)d_in[9];
    const float* cosp = (const float*)d_in[10];
    const float* sinp = (const float*)d_in[11];
    float* out = (float*)d_out;

    const size_t per = (size_t)B * NH * S * HD;   // 3,145,728
    u16* ws    = (u16*)d_ws;
    u16* hsb   = ws;                              // bf16 hidden  [BS,H]
    u16* WTqkv = hsb + per;                       // bf16 [2304,768] (Q/K rotated)
    u16* WTo   = WTqkv + (size_t)3 * H * H;       // bf16 [768,768]
    u16* QTb   = WTo + (size_t)H * H;             // bf16 [B,NH,HD,S] (transposed)
    u16* Kb    = QTb + per;                       // bf16 [B,NH,S,HD]
    u16* VT    = Kb + per;                        // bf16 [B,NH,HD,S]
    u16* ctxb  = VT + per;                        // bf16 [BS,H]
    float* bqk2 = (float*)(ctxb + per);           // rotated biases [2*H]

    prep_kernel<<<576 + (BS * H) / 2048, 256, 0, stream>>>(
        hs, Wq, Wk, Wv, Wo, bq, bk, cosp, sinp, hsb, WTqkv, WTo, bqk2);

    gemm_qkv_kernel<<<(BS / 128) * (2304 / 64), 256, 0, stream>>>(
        hsb, WTqkv, bqk2, bv, QTb, Kb, VT);

    attn_mfma_kernel<<<(S / 64) * (B * NH), 256, 0, stream>>>(
        QTb, Kb, VT, mask, ctxb);

    gemm_out_kernel<<<(BS / 128) * (H / 64), 256, 0, stream>>>(
        ctxb, WTo, bo, out);
}